// Round 16
// baseline (211.434 us; speedup 1.0000x reference)
//
#include <hip/hip_runtime.h>
#include <stdint.h>

#define NSEL 300
#define BB 2
#define QQ 900
#define CC 91
#define NQC (QQ * CC)   // 81900
#define NV4 (NQC / 4)   // 20475 (exact)
#define CH4 1280        // vec4 chunk per hist block (16*1280 >= 20475)
#define MH 128
#define MW 128
#define TGT 512

#define NBUCKET 4096
#define CAND_CAP 4096

typedef float floatx4 __attribute__((ext_vector_type(4)));

// ---- d_ws byte offsets ----
#define WS_KEYS   0               // u32 [2][81900]  (655200 B, pad to 655360)
#define WS_GHIST  655360          // u32 [2][4096]   (32768 B) -- memset 0 per call
#define WS_SEL    688128          // int [600]

// ---------------- K1: keys + LDS hist -> global atomic hist ----------------
__global__ __launch_bounds__(256) void hist_kernel(
    const float* __restrict__ logits, uint8_t* __restrict__ ws)
{
    __shared__ uint32_t hist[NBUCKET];
    const int blk   = blockIdx.x;          // 0..31
    const int b     = blk >> 4;
    const int chunk = blk & 15;

    uint32_t* keys  = (uint32_t*)(ws + WS_KEYS) + (size_t)b * NQC;
    uint32_t* ghist = (uint32_t*)(ws + WS_GHIST) + (size_t)b * NBUCKET;

    for (int i = threadIdx.x; i < NBUCKET; i += 256) hist[i] = 0u;
    __syncthreads();

    const int base = chunk * CH4;
    int end = base + CH4; if (end > NV4) end = NV4;
    const float4* lg4   = (const float4*)(logits + (size_t)b * NQC);
    uint4*        keys4 = (uint4*)keys;

    for (int v = base + threadIdx.x; v < end; v += 256) {
        float4 x = lg4[v];
        uint4 k;
        k.x = __float_as_uint(1.0f / (1.0f + expf(-x.x)));   // identical math
        k.y = __float_as_uint(1.0f / (1.0f + expf(-x.y)));
        k.z = __float_as_uint(1.0f / (1.0f + expf(-x.z)));
        k.w = __float_as_uint(1.0f / (1.0f + expf(-x.w)));
        keys4[v] = k;
        atomicAdd(&hist[k.x >> 18], 1u);
        atomicAdd(&hist[k.y >> 18], 1u);
        atomicAdd(&hist[k.z >> 18], 1u);
        atomicAdd(&hist[k.w >> 18], 1u);
    }
    __syncthreads();

    // merge nonzero buckets into the global histogram (device-scope atomics)
    for (int i = threadIdx.x; i < NBUCKET; i += 256) {
        uint32_t c = hist[i];
        if (c) atomicAdd(&ghist[i], c);
    }
}

// -------- K2: ghist scan (registers) + vec collect + rank-select ----------
__global__ __launch_bounds__(1024) void select_kernel(
    const float* __restrict__ boxes_in,  // [B,Q,4]
    const float* __restrict__ logvars,   // [B,Q,4]
    const int*   __restrict__ tsizes,    // [B,2]
    float* __restrict__ out,
    uint8_t* __restrict__ ws)
{
    __shared__ unsigned long long cand[CAND_CAP];
    __shared__ uint32_t wsum[16];
    __shared__ int s_count;
    __shared__ int s_cut;

    const int b    = blockIdx.x;
    const int tid  = threadIdx.x;
    const int lane = tid & 63;
    const int wid  = tid >> 6;

    if (tid == 0) s_count = 0;

    // Each thread owns buckets 4tid..4tid+3 (16KB global hist, one uint4 load).
    const uint32_t* ghist = (const uint32_t*)(ws + WS_GHIST)
                          + (size_t)b * NBUCKET;
    const uint4 h = *(const uint4*)(ghist + 4 * tid);
    const uint32_t val = h.x + h.y + h.z + h.w;

    // Wave-level reverse inclusive scan (suffix within wave) -- proven R10.
    uint32_t acc = val;
    #pragma unroll
    for (int off = 1; off < 64; off <<= 1) {
        uint32_t o = __shfl_down(acc, off, 64);
        if (lane + off < 64) acc += o;
    }
    if (lane == 0) wsum[wid] = acc;      // wave total (suffix at lane 0)
    __syncthreads();

    uint32_t later = 0;
    for (int w = wid + 1; w < 16; ++w) later += wsum[w];
    const uint32_t sfx      = acc + later;   // sum over threads >= tid
    const uint32_t sfx_next = sfx - val;

    if (sfx >= NSEL && sfx_next < NSEL) {
        // crossing thread: refine to bucket granularity (registers only)
        int a = (int)sfx_next;
        int cut = 4 * tid;
        const uint32_t hh[4] = { h.x, h.y, h.z, h.w };
        for (int k = 3; k >= 0; --k) {
            a += (int)hh[k];
            if (a >= NSEL) { cut = 4 * tid + k; break; }
        }
        s_cut = cut;
    }
    __syncthreads();
    const uint32_t cut = (uint32_t)s_cut;

    // Collect candidates >= cut into LDS (vectorized key reads).
    const uint4* keys4 = (const uint4*)((const uint32_t*)(ws + WS_KEYS)
                                        + (size_t)b * NQC);
    for (int v = tid; v < NV4; v += 1024) {
        const uint4 k = keys4[v];
        const int i0 = 4 * v;
        const uint32_t kk[4] = { k.x, k.y, k.z, k.w };
        #pragma unroll
        for (int u = 0; u < 4; ++u) {
            if ((kk[u] >> 18) >= cut) {
                int pos = atomicAdd(&s_count, 1);
                if (pos < CAND_CAP) {
                    cand[pos] = ((unsigned long long)kk[u] << 32)
                              | (uint32_t)(~(uint32_t)(i0 + u));
                }
            }
        }
    }
    __syncthreads();

    int count = s_count;
    if (count > CAND_CAP) count = CAND_CAP;

    float* out_scores = out;                 // [B*NSEL]
    float* out_labels = out + 600;
    float* out_boxes  = out + 1200;
    float* out_unc    = out + 3600;
    int*   sel        = (int*)(ws + WS_SEL);

    // Rank-select: rank = #candidates with larger composite key.
    // Unique keys => ranks are a permutation; rank<NSEL writes slot directly.
    // Matches descending sort with lower-index-first ties (low word = ~index).
    for (int i = tid; i < count; i += 1024) {
        const unsigned long long my = cand[i];
        int r = 0;
        for (int j = 0; j < count; ++j) r += (cand[j] > my) ? 1 : 0;
        if (r < NSEL) {
            const uint32_t key = (uint32_t)(my >> 32);
            const uint32_t idx = ~((uint32_t)(my & 0xFFFFFFFFull));
            const int q = (int)(idx / CC);
            const int label = (int)(idx - (uint32_t)q * CC);
            const int o = b * NSEL + r;

            out_scores[o] = __uint_as_float(key);
            out_labels[o] = (float)label;

            const float* bx = boxes_in + ((size_t)(b * QQ + q)) * 4;
            float cx = bx[0], cy = bx[1], w = bx[2], hgt = bx[3];
            float hh2 = (float)tsizes[b * 2 + 0];
            float ww2 = (float)tsizes[b * 2 + 1];
            out_boxes[o * 4 + 0] = (cx - 0.5f * w) * ww2;
            out_boxes[o * 4 + 1] = (cy - 0.5f * hgt) * hh2;
            out_boxes[o * 4 + 2] = (cx + 0.5f * w) * ww2;
            out_boxes[o * 4 + 3] = (cy + 0.5f * hgt) * hh2;

            const float* gv = logvars + ((size_t)(b * QQ + q)) * 4;
            float s0 = gv[0] + gv[1];
            float s1 = s0 + gv[2];
            float s2 = s1 + gv[3];
            out_unc[o] = s2 * 0.25f;

            sel[o] = q;
        }
    }
}

// ---------------- K3: bilinear upsample 128->512 + threshold ----------
// Barrier-free variant: NO LDS, no __syncthreads. Each thread reads its
// 10 rows x 3 cols directly from global (wave-coalesced, L1/L2-hot input),
// computes the bit-identical h[10] blends, then the proven 8x4 nt-burst
// store phase. Waves are fully independent streaming units.
__global__ __launch_bounds__(256) void mask_kernel(
    const float* __restrict__ masks_in,  // [B,Q,128,128]
    const int*   __restrict__ sel,       // [B*NSEL]
    float* __restrict__ out_masks)       // [B*NSEL,512,512]
{
    const int xg = threadIdx.x & 127;    // output cols 4xg..4xg+3
    const int rh = threadIdx.x >> 7;     // row half (0/1) within 64-row item
    const int cm1 = (xg == 0)   ? 0   : xg - 1;
    const int cp1 = (xg == 127) ? 127 : xg + 1;
    const bool eL = (xg == 0);
    const bool eR = (xg == 127);

    const int it0 = 3 * blockIdx.x;      // exactly 3 items per block
    for (int item = it0; item < it0 + 3; ++item) {
        const int m = item >> 3;         // 0..599
        const int e = item & 7;          // eighth: 64 rows
        const int b = m / NSEL;
        const int q = sel[m];

        const float* src = masks_in + ((size_t)(b * QQ + q)) * (MH * MW);
        float* dst = out_masks + (size_t)m * (TGT * TGT);

        // ---- Phase 1: horizontal blends, direct coalesced global reads ----
        const int k0    = 16 * e + 8 * rh;   // first out-row group index
        const int rbase = k0 - 1;
        floatx4 h[10];
        #pragma unroll
        for (int j = 0; j < 10; ++j) {
            int r = rbase + j;
            r = (r < 0) ? 0 : (r > MH - 1 ? MH - 1 : r);
            const float* R = src + (size_t)r * MW;
            const float a = R[cm1];
            const float c = R[xg];
            const float p = R[cp1];
            floatx4 v;
            v.x = eL ? c : fmaf(0.375f, a, 0.625f * c);
            v.y = eL ? c : fmaf(0.125f, a, 0.875f * c);
            v.z = eR ? c : fmaf(0.125f, p, 0.875f * c);
            v.w = eR ? c : fmaf(0.375f, p, 0.625f * c);
            h[j] = v;
        }

        // ---- Phase 2: vertical lerps + burst nt-stores ----
        float* dhalf = dst + (size_t)(k0 * 4) * TGT + 4 * xg;
        #pragma unroll
        for (int g = 0; g < 8; ++g) {
            const floatx4 hA = h[g];
            const floatx4 hB = h[g + 1];
            const floatx4 hC = h[g + 2];
            const floatx4 dAB = hB - hA;
            const floatx4 dBC = hC - hB;

            floatx4 vA, vB, vC, vD;
            #pragma unroll
            for (int u = 0; u < 4; ++u) {
                vA[u] = fmaf(0.625f, dAB[u], hA[u]);
                vB[u] = fmaf(0.875f, dAB[u], hA[u]);
                vC[u] = fmaf(0.125f, dBC[u], hB[u]);
                vD[u] = fmaf(0.375f, dBC[u], hB[u]);
            }
            floatx4 rA, rB, rC, rD;
            #pragma unroll
            for (int u = 0; u < 4; ++u) {
                rA[u] = (vA[u] > 0.0f) ? 1.0f : 0.0f;
                rB[u] = (vB[u] > 0.0f) ? 1.0f : 0.0f;
                rC[u] = (vC[u] > 0.0f) ? 1.0f : 0.0f;
                rD[u] = (vD[u] > 0.0f) ? 1.0f : 0.0f;
            }
            floatx4* p0 = (floatx4*)(dhalf + (size_t)(4 * g    ) * TGT);
            floatx4* p1 = (floatx4*)(dhalf + (size_t)(4 * g + 1) * TGT);
            floatx4* p2 = (floatx4*)(dhalf + (size_t)(4 * g + 2) * TGT);
            floatx4* p3 = (floatx4*)(dhalf + (size_t)(4 * g + 3) * TGT);
            __builtin_nontemporal_store(rA, p0);
            __builtin_nontemporal_store(rB, p1);
            __builtin_nontemporal_store(rC, p2);
            __builtin_nontemporal_store(rD, p3);
        }
    }
}

extern "C" void kernel_launch(void* const* d_in, const int* in_sizes, int n_in,
                              void* d_out, int out_size, void* d_ws, size_t ws_size,
                              hipStream_t stream) {
    (void)in_sizes; (void)n_in; (void)out_size; (void)ws_size;

    const float* pred_logits  = (const float*)d_in[0];  // [2,900,91]
    const float* pred_boxes   = (const float*)d_in[1];  // [2,900,4]
    const float* pred_masks   = (const float*)d_in[2];  // [2,900,128,128]
    const float* pred_logvars = (const float*)d_in[3];  // [2,900,4]
    const int*   target_sizes = (const int*)d_in[4];    // [2,2]

    float*   out = (float*)d_out;
    uint8_t* ws  = (uint8_t*)d_ws;

    // Zero the global histogram each call (replay-deterministic; graph-safe).
    hipMemsetAsync(ws + WS_GHIST, 0, BB * NBUCKET * sizeof(uint32_t), stream);

    hipLaunchKernelGGL(hist_kernel, dim3(32), dim3(256), 0, stream,
                       pred_logits, ws);
    hipLaunchKernelGGL(select_kernel, dim3(BB), dim3(1024), 0, stream,
                       pred_boxes, pred_logvars, target_sizes, out, ws);

    float* out_masks = out + 4200;
    const int* sel = (const int*)(ws + WS_SEL);
    hipLaunchKernelGGL(mask_kernel, dim3(1600), dim3(256), 0, stream,
                       pred_masks, sel, out_masks);
}

// Round 17
// 193.698 us; speedup vs baseline: 1.0916x; 1.0916x over previous
//
#include <hip/hip_runtime.h>
#include <stdint.h>

#define NSEL 300
#define BB 2
#define QQ 900
#define CC 91
#define NQC (QQ * CC)   // 81900
#define NV4 (NQC / 4)   // 20475 (exact)
#define CH4 1280        // vec4 chunk per hist block (16*1280 >= 20475)
#define MH 128
#define MW 128
#define TGT 512

#define NBUCKET 4096
#define CAND_CAP 4096
#define NCHUNK 16

typedef float floatx4 __attribute__((ext_vector_type(4)));

// ---- d_ws byte offsets ----
#define WS_KEYS   0               // u32 [2][81900]  (655200 B, pad to 655360)
#define WS_PART   655360          // u32 [2*16][4096] (524288 B) -- no init needed
#define WS_SEL    1179648         // int [600]

// ---------------- K1: keys + LDS hist -> per-block partial (no atomics) -----
__global__ __launch_bounds__(256) void hist_kernel(
    const float* __restrict__ logits, uint8_t* __restrict__ ws)
{
    __shared__ uint32_t hist[NBUCKET];
    const int blk   = blockIdx.x;          // 0..31
    const int b     = blk >> 4;
    const int chunk = blk & 15;

    uint32_t* keys = (uint32_t*)(ws + WS_KEYS) + (size_t)b * NQC;
    uint32_t* part = (uint32_t*)(ws + WS_PART) + (size_t)blk * NBUCKET;

    for (int i = threadIdx.x; i < NBUCKET; i += 256) hist[i] = 0u;
    __syncthreads();

    const int base = chunk * CH4;
    int end = base + CH4; if (end > NV4) end = NV4;
    const float4* lg4   = (const float4*)(logits + (size_t)b * NQC);
    uint4*        keys4 = (uint4*)keys;

    for (int v = base + threadIdx.x; v < end; v += 256) {
        float4 x = lg4[v];
        uint4 k;
        k.x = __float_as_uint(1.0f / (1.0f + expf(-x.x)));   // identical math
        k.y = __float_as_uint(1.0f / (1.0f + expf(-x.y)));
        k.z = __float_as_uint(1.0f / (1.0f + expf(-x.z)));
        k.w = __float_as_uint(1.0f / (1.0f + expf(-x.w)));
        keys4[v] = k;
        atomicAdd(&hist[k.x >> 18], 1u);
        atomicAdd(&hist[k.y >> 18], 1u);
        atomicAdd(&hist[k.z >> 18], 1u);
        atomicAdd(&hist[k.w >> 18], 1u);
    }
    __syncthreads();

    for (int i = threadIdx.x; i < NBUCKET; i += 256) part[i] = hist[i];
}

// -------- K2: partial-reduce + scan (registers) + vec collect + rank --------
__global__ __launch_bounds__(1024) void select_kernel(
    const float* __restrict__ boxes_in,  // [B,Q,4]
    const float* __restrict__ logvars,   // [B,Q,4]
    const int*   __restrict__ tsizes,    // [B,2]
    float* __restrict__ out,
    uint8_t* __restrict__ ws)
{
    __shared__ unsigned long long cand[CAND_CAP];
    __shared__ uint32_t wsum[16];
    __shared__ int s_count;
    __shared__ int s_cut;

    const int b    = blockIdx.x;
    const int tid  = threadIdx.x;
    const int lane = tid & 63;
    const int wid  = tid >> 6;

    if (tid == 0) s_count = 0;

    // Each thread owns buckets 4tid..4tid+3: reduce 16 partials (uint4 each).
    const uint32_t* part = (const uint32_t*)(ws + WS_PART)
                         + (size_t)b * NCHUNK * NBUCKET;
    uint4 h = make_uint4(0u, 0u, 0u, 0u);
    #pragma unroll
    for (int p = 0; p < NCHUNK; ++p) {
        uint4 v = *(const uint4*)(part + (size_t)p * NBUCKET + 4 * tid);
        h.x += v.x; h.y += v.y; h.z += v.z; h.w += v.w;
    }
    const uint32_t val = h.x + h.y + h.z + h.w;

    // Wave-level reverse inclusive scan (suffix within wave) -- proven.
    uint32_t acc = val;
    #pragma unroll
    for (int off = 1; off < 64; off <<= 1) {
        uint32_t o = __shfl_down(acc, off, 64);
        if (lane + off < 64) acc += o;
    }
    if (lane == 0) wsum[wid] = acc;      // wave total (suffix at lane 0)
    __syncthreads();

    uint32_t later = 0;
    for (int w = wid + 1; w < 16; ++w) later += wsum[w];
    const uint32_t sfx      = acc + later;   // sum over threads >= tid
    const uint32_t sfx_next = sfx - val;

    if (sfx >= NSEL && sfx_next < NSEL) {
        // crossing thread: refine to bucket granularity (registers only)
        int a = (int)sfx_next;
        int cut = 4 * tid;
        const uint32_t hh[4] = { h.x, h.y, h.z, h.w };
        for (int k = 3; k >= 0; --k) {
            a += (int)hh[k];
            if (a >= NSEL) { cut = 4 * tid + k; break; }
        }
        s_cut = cut;
    }
    __syncthreads();
    const uint32_t cut = (uint32_t)s_cut;

    // Collect candidates >= cut into LDS (vectorized key reads).
    const uint4* keys4 = (const uint4*)((const uint32_t*)(ws + WS_KEYS)
                                        + (size_t)b * NQC);
    for (int v = tid; v < NV4; v += 1024) {
        const uint4 k = keys4[v];
        const int i0 = 4 * v;
        const uint32_t kk[4] = { k.x, k.y, k.z, k.w };
        #pragma unroll
        for (int u = 0; u < 4; ++u) {
            if ((kk[u] >> 18) >= cut) {
                int pos = atomicAdd(&s_count, 1);
                if (pos < CAND_CAP) {
                    cand[pos] = ((unsigned long long)kk[u] << 32)
                              | (uint32_t)(~(uint32_t)(i0 + u));
                }
            }
        }
    }
    __syncthreads();

    int count = s_count;
    if (count > CAND_CAP) count = CAND_CAP;

    float* out_scores = out;                 // [B*NSEL]
    float* out_labels = out + 600;
    float* out_boxes  = out + 1200;
    float* out_unc    = out + 3600;
    int*   sel        = (int*)(ws + WS_SEL);

    // Rank-select: rank = #candidates with larger composite key.
    // Unique keys => ranks are a permutation; rank<NSEL writes slot directly.
    // Matches descending sort with lower-index-first ties (low word = ~index).
    for (int i = tid; i < count; i += 1024) {
        const unsigned long long my = cand[i];
        int r = 0;
        for (int j = 0; j < count; ++j) r += (cand[j] > my) ? 1 : 0;
        if (r < NSEL) {
            const uint32_t key = (uint32_t)(my >> 32);
            const uint32_t idx = ~((uint32_t)(my & 0xFFFFFFFFull));
            const int q = (int)(idx / CC);
            const int label = (int)(idx - (uint32_t)q * CC);
            const int o = b * NSEL + r;

            out_scores[o] = __uint_as_float(key);
            out_labels[o] = (float)label;

            const float* bx = boxes_in + ((size_t)(b * QQ + q)) * 4;
            float cx = bx[0], cy = bx[1], w = bx[2], hgt = bx[3];
            float hh2 = (float)tsizes[b * 2 + 0];
            float ww2 = (float)tsizes[b * 2 + 1];
            out_boxes[o * 4 + 0] = (cx - 0.5f * w) * ww2;
            out_boxes[o * 4 + 1] = (cy - 0.5f * hgt) * hh2;
            out_boxes[o * 4 + 2] = (cx + 0.5f * w) * ww2;
            out_boxes[o * 4 + 3] = (cy + 0.5f * hgt) * hh2;

            const float* gv = logvars + ((size_t)(b * QQ + q)) * 4;
            float s0 = gv[0] + gv[1];
            float s1 = s0 + gv[2];
            float s2 = s1 + gv[3];
            out_unc[o] = s2 * 0.25f;

            sel[o] = q;
        }
    }
}

// ---------------- K3: bilinear upsample 128->512 + threshold ----------
// Byte-identical to R15/R10 best: 1600 blocks x 3 items, LDS stage,
// register-cached blends + burst nt-stores.
__global__ __launch_bounds__(256) void mask_kernel(
    const float* __restrict__ masks_in,  // [B,Q,128,128]
    const int*   __restrict__ sel,       // [B*NSEL]
    float* __restrict__ out_masks)       // [B*NSEL,512,512]
{
    __shared__ float S[18 * MW];         // 9216 B

    const int xg = threadIdx.x & 127;    // output cols 4xg..4xg+3
    const int rh = threadIdx.x >> 7;     // row half (0/1) within 64-row item
    const int cm1 = (xg == 0)   ? 0   : xg - 1;
    const int cp1 = (xg == 127) ? 127 : xg + 1;
    const bool eL = (xg == 0);
    const bool eR = (xg == 127);

    const int it0 = 3 * blockIdx.x;      // exactly 3 items per block
    for (int item = it0; item < it0 + 3; ++item) {
        const int m = item >> 3;         // 0..599
        const int e = item & 7;          // eighth: 64 rows
        const int b = m / NSEL;
        const int q = sel[m];

        const float* src = masks_in + ((size_t)(b * QQ + q)) * (MH * MW);
        float* dst = out_masks + (size_t)m * (TGT * TGT);

        const int y0   = e * 64;
        const int r_lo = (e == 0) ? 0   : (16 * e - 1);
        const int r_hi = (e == 7) ? 127 : (16 * e + 16);
        const int nrows = r_hi - r_lo + 1;   // 17 or 18

        {
            const float4* s4 = (const float4*)(src + (size_t)r_lo * MW);
            float4* d4 = (float4*)S;
            const int n4 = nrows * (MW / 4);
            for (int i = threadIdx.x; i < n4; i += 256) d4[i] = s4[i];
        }
        __syncthreads();

        // ---- Phase 1: horizontal blends for input rows k0-1 .. k0+8 ----
        const int k0    = 16 * e + 8 * rh;   // first out-row group index
        const int rbase = k0 - 1;
        floatx4 h[10];
        #pragma unroll
        for (int j = 0; j < 10; ++j) {
            int r = rbase + j;
            r = (r < 0) ? 0 : (r > MH - 1 ? MH - 1 : r);
            const float* R = S + (r - r_lo) * MW;
            const float a = R[cm1];
            const float c = R[xg];
            const float p = R[cp1];
            floatx4 v;
            v.x = eL ? c : fmaf(0.375f, a, 0.625f * c);
            v.y = eL ? c : fmaf(0.125f, a, 0.875f * c);
            v.z = eR ? c : fmaf(0.125f, p, 0.875f * c);
            v.w = eR ? c : fmaf(0.375f, p, 0.625f * c);
            h[j] = v;
        }

        // ---- Phase 2: vertical lerps + burst stores ----
        float* dhalf = dst + (size_t)(y0 + rh * 32) * TGT + 4 * xg;
        #pragma unroll
        for (int g = 0; g < 8; ++g) {
            const floatx4 hA = h[g];
            const floatx4 hB = h[g + 1];
            const floatx4 hC = h[g + 2];
            const floatx4 dAB = hB - hA;
            const floatx4 dBC = hC - hB;

            floatx4 vA, vB, vC, vD;
            #pragma unroll
            for (int u = 0; u < 4; ++u) {
                vA[u] = fmaf(0.625f, dAB[u], hA[u]);
                vB[u] = fmaf(0.875f, dAB[u], hA[u]);
                vC[u] = fmaf(0.125f, dBC[u], hB[u]);
                vD[u] = fmaf(0.375f, dBC[u], hB[u]);
            }
            floatx4 rA, rB, rC, rD;
            #pragma unroll
            for (int u = 0; u < 4; ++u) {
                rA[u] = (vA[u] > 0.0f) ? 1.0f : 0.0f;
                rB[u] = (vB[u] > 0.0f) ? 1.0f : 0.0f;
                rC[u] = (vC[u] > 0.0f) ? 1.0f : 0.0f;
                rD[u] = (vD[u] > 0.0f) ? 1.0f : 0.0f;
            }
            floatx4* p0 = (floatx4*)(dhalf + (size_t)(4 * g    ) * TGT);
            floatx4* p1 = (floatx4*)(dhalf + (size_t)(4 * g + 1) * TGT);
            floatx4* p2 = (floatx4*)(dhalf + (size_t)(4 * g + 2) * TGT);
            floatx4* p3 = (floatx4*)(dhalf + (size_t)(4 * g + 3) * TGT);
            __builtin_nontemporal_store(rA, p0);
            __builtin_nontemporal_store(rB, p1);
            __builtin_nontemporal_store(rC, p2);
            __builtin_nontemporal_store(rD, p3);
        }
        __syncthreads();   // LDS reuse guard before next item's stage
    }
}

extern "C" void kernel_launch(void* const* d_in, const int* in_sizes, int n_in,
                              void* d_out, int out_size, void* d_ws, size_t ws_size,
                              hipStream_t stream) {
    (void)in_sizes; (void)n_in; (void)out_size; (void)ws_size;

    const float* pred_logits  = (const float*)d_in[0];  // [2,900,91]
    const float* pred_boxes   = (const float*)d_in[1];  // [2,900,4]
    const float* pred_masks   = (const float*)d_in[2];  // [2,900,128,128]
    const float* pred_logvars = (const float*)d_in[3];  // [2,900,4]
    const int*   target_sizes = (const int*)d_in[4];    // [2,2]

    float*   out = (float*)d_out;
    uint8_t* ws  = (uint8_t*)d_ws;

    hipLaunchKernelGGL(hist_kernel, dim3(32), dim3(256), 0, stream,
                       pred_logits, ws);
    hipLaunchKernelGGL(select_kernel, dim3(BB), dim3(1024), 0, stream,
                       pred_boxes, pred_logvars, target_sizes, out, ws);

    float* out_masks = out + 4200;
    const int* sel = (const int*)(ws + WS_SEL);
    hipLaunchKernelGGL(mask_kernel, dim3(1600), dim3(256), 0, stream,
                       pred_masks, sel, out_masks);
}